// Round 1
// baseline (190.656 us; speedup 1.0000x reference)
//
#include <hip/hip_runtime.h>

// Problem: CausalSelfAttention  B=2 T=2048 C=1024 H=16 D=64, fp32 in/out.
// Pipeline: cvt(x) -> tconv(Wqkv,Wout) -> GEMM1(bf16) -> rope_pack -> vtrans
//           -> flash attn -> GEMM2(fp32 out).

#define B_  2
#define T_  2048
#define C_  1024
#define H_  16
#define D_  64
#define N3_ 3072

typedef unsigned short ushortx8 __attribute__((ext_vector_type(8)));
typedef unsigned short ushortx4 __attribute__((ext_vector_type(4)));
typedef short bf16x8 __attribute__((ext_vector_type(8)));
typedef float f32x4 __attribute__((ext_vector_type(4)));

__device__ __forceinline__ unsigned short f2bf(float f) {
  union { float f; unsigned u; } v; v.f = f;
  unsigned r = v.u + 0x7FFFu + ((v.u >> 16) & 1u);   // RNE
  return (unsigned short)(r >> 16);
}
__device__ __forceinline__ float bf2f(unsigned short h) {
  union { unsigned u; float f; } v; v.u = ((unsigned)h) << 16;
  return v.f;
}
// async global->LDS, 16B per lane; dst must be wave-uniform (HW adds lane*16)
__device__ __forceinline__ void gload_lds16(const void* g, void* l) {
  __builtin_amdgcn_global_load_lds((const __attribute__((address_space(1))) void*)g,
                                   (__attribute__((address_space(3))) void*)l,
                                   16, 0, 0);
}

// ---------------- fp32 -> bf16 convert (x) ----------------
__global__ __launch_bounds__(256) void cvt_x_kernel(const float* __restrict__ x,
                                                    unsigned short* __restrict__ xb) {
  size_t i = ((size_t)blockIdx.x * 256 + threadIdx.x) * 4;
  const float4 v = *(const float4*)(x + i);
  ushortx4 o;
  o[0] = f2bf(v.x); o[1] = f2bf(v.y); o[2] = f2bf(v.z); o[3] = f2bf(v.w);
  *(ushortx4*)(xb + i) = o;
}

// ------------- transpose+convert: W[K][N] f32 -> WT[N][K] bf16 -------------
__global__ __launch_bounds__(256) void tconv_kernel(const float* __restrict__ W,
                                                    unsigned short* __restrict__ WT,
                                                    int K, int N) {
  __shared__ float tile[32][33];
  const int n0 = blockIdx.x * 32, k0 = blockIdx.y * 32;
  const int tx = threadIdx.x & 31, ty = threadIdx.x >> 5;
#pragma unroll
  for (int i = 0; i < 4; ++i)
    tile[ty + i * 8][tx] = W[(size_t)(k0 + ty + i * 8) * N + n0 + tx];
  __syncthreads();
#pragma unroll
  for (int i = 0; i < 4; ++i)
    WT[(size_t)(n0 + ty + i * 8) * K + k0 + tx] = f2bf(tile[tx][ty + i * 8]);
}

// ---------------- GEMM: C[M][N] = A[M][K] * BT[N][K]^T (bf16 MFMA) ----------------
// 128x128 tile, BK=64, 4 waves (each 64x64), global_load_lds w/ XOR-swizzled source.
template <int OUTF32>
__global__ __launch_bounds__(256) void gemm_bt_kernel(const unsigned short* __restrict__ A,
                                                      const unsigned short* __restrict__ BT,
                                                      void* __restrict__ Cptr,
                                                      int M, int N, int K) {
  __shared__ unsigned short Alds[128 * 64];
  __shared__ unsigned short Blds[128 * 64];
  const int tid = threadIdx.x;
  const int w = tid >> 6, l = tid & 63;
  const int wr = w >> 1, wc = w & 1;
  const int lg = l >> 4, lr = l & 15;
  const int m0 = blockIdx.y * 128, n0 = blockIdx.x * 128;
  const int lr8 = l >> 3;                 // row within 8-row chunk
  const int lc8 = (l & 7) ^ lr8;          // pre-swizzled source col16 (T2 st-style)

  f32x4 acc[4][4];
#pragma unroll
  for (int i = 0; i < 4; ++i)
#pragma unroll
    for (int j = 0; j < 4; ++j) acc[i][j] = f32x4{0.f, 0.f, 0.f, 0.f};

  for (int k0 = 0; k0 < K; k0 += 64) {
    __syncthreads();
#pragma unroll
    for (int i = 0; i < 4; ++i) {
      const int ch = w * 4 + i;           // 16 chunks of 1024B per tile
      gload_lds16(A + (size_t)(m0 + ch * 8 + lr8) * K + k0 + lc8 * 8, &Alds[ch * 512]);
      gload_lds16(BT + (size_t)(n0 + ch * 8 + lr8) * K + k0 + lc8 * 8, &Blds[ch * 512]);
    }
    __syncthreads();
#pragma unroll
    for (int kc = 0; kc < 2; ++kc) {
      bf16x8 af[4], bfr[4];
#pragma unroll
      for (int mi = 0; mi < 4; ++mi) {
        const int row = wr * 64 + mi * 16 + lr;
        const int c16 = (kc * 4 + lg) ^ (row & 7);
        af[mi] = *(const bf16x8*)(&Alds[row * 64 + c16 * 8]);
      }
#pragma unroll
      for (int nj = 0; nj < 4; ++nj) {
        const int row = wc * 64 + nj * 16 + lr;
        const int c16 = (kc * 4 + lg) ^ (row & 7);
        bfr[nj] = *(const bf16x8*)(&Blds[row * 64 + c16 * 8]);
      }
#pragma unroll
      for (int mi = 0; mi < 4; ++mi)
#pragma unroll
        for (int nj = 0; nj < 4; ++nj)
          acc[mi][nj] = __builtin_amdgcn_mfma_f32_16x16x32_bf16(af[mi], bfr[nj], acc[mi][nj], 0, 0, 0);
    }
  }
#pragma unroll
  for (int mi = 0; mi < 4; ++mi)
#pragma unroll
    for (int nj = 0; nj < 4; ++nj)
#pragma unroll
      for (int j = 0; j < 4; ++j) {
        const int row = m0 + wr * 64 + mi * 16 + lg * 4 + j;  // C/D: row=(lane>>4)*4+j
        const int col = n0 + wc * 64 + nj * 16 + lr;          //      col=lane&15
        if (OUTF32) ((float*)Cptr)[(size_t)row * N + col] = acc[mi][nj][j];
        else ((unsigned short*)Cptr)[(size_t)row * N + col] = f2bf(acc[mi][nj][j]);
      }
}

// ---------------- RoPE + pack Q,K to [bh][T][64] (q pre-scaled 1/8) ----------------
__global__ __launch_bounds__(256) void rope_pack_kernel(const unsigned short* __restrict__ QKV,
                                                        unsigned short* __restrict__ Qp,
                                                        unsigned short* __restrict__ Kp) {
  const int tt = blockIdx.x, bh = blockIdx.y;
  const int b = bh >> 4, h = bh & 15;
  const int tid = threadIdx.x;
  const int half = tid >> 7;           // 0=q, 1=k
  const int r = (tid >> 1) & 63;
  const int d0 = (tid & 1) * 16;
  const int t = tt * 64 + r;
  const unsigned short* src = QKV + (size_t)(b * T_ + t) * N3_ + half * C_ + h * D_;
  ushortx8 lo0 = *(const ushortx8*)(src + d0);
  ushortx8 lo1 = *(const ushortx8*)(src + d0 + 8);
  ushortx8 hi0 = *(const ushortx8*)(src + d0 + 32);
  ushortx8 hi1 = *(const ushortx8*)(src + d0 + 40);
  ushortx8 olo0, olo1, ohi0, ohi1;
  const float scale = half ? 1.0f : 0.125f;   // 1/sqrt(64) folded into q
  const float tf = (float)t;
#pragma unroll
  for (int jj = 0; jj < 16; ++jj) {
    const int d = d0 + jj;
    // inv_freq = 10000^(-d/32) = 2^(-d*log2(10000)/32)
    const float invf = exp2f((float)d * -0.41524101186092036f);
    const float ang = tf * invf;
    const float c = cosf(ang), s = sinf(ang);
    const float xl = bf2f(jj < 8 ? lo0[jj] : lo1[jj - 8]);
    const float xh = bf2f(jj < 8 ? hi0[jj] : hi1[jj - 8]);
    const unsigned short rl = f2bf((xl * c - xh * s) * scale);
    const unsigned short rh = f2bf((xh * c + xl * s) * scale);
    if (jj < 8) { olo0[jj] = rl; ohi0[jj] = rh; }
    else        { olo1[jj - 8] = rl; ohi1[jj - 8] = rh; }
  }
  unsigned short* dst = (half ? Kp : Qp) + ((size_t)bh * T_ + t) * D_;
  *(ushortx8*)(dst + d0) = olo0;
  *(ushortx8*)(dst + d0 + 8) = olo1;
  *(ushortx8*)(dst + d0 + 32) = ohi0;
  *(ushortx8*)(dst + d0 + 40) = ohi1;
}

// ---------------- V transpose: qkv v-cols -> Vt[bh][64][T] ----------------
__global__ __launch_bounds__(256) void vtrans_kernel(const unsigned short* __restrict__ QKV,
                                                     unsigned short* __restrict__ Vt) {
  __shared__ unsigned short tile[64][72];
  const int tt = blockIdx.x, bh = blockIdx.y;
  const int b = bh >> 4, h = bh & 15;
  const int tid = threadIdx.x;
  {
    const int r = tid >> 2, seg = tid & 3;
    const unsigned short* src = QKV + (size_t)(b * T_ + tt * 64 + r) * N3_ + 2 * C_ + h * D_ + seg * 16;
    *(ushortx8*)(&tile[r][seg * 16]) = *(const ushortx8*)(src);
    *(ushortx8*)(&tile[r][seg * 16 + 8]) = *(const ushortx8*)(src + 8);
  }
  __syncthreads();
  {
    const int d = tid >> 2, ts = tid & 3;
    ushortx8 o0, o1;
#pragma unroll
    for (int i = 0; i < 8; ++i) { o0[i] = tile[ts * 16 + i][d]; o1[i] = tile[ts * 16 + 8 + i][d]; }
    unsigned short* dst = Vt + ((size_t)bh * D_ + d) * T_ + tt * 64 + ts * 16;
    *(ushortx8*)(dst) = o0;
    *(ushortx8*)(dst + 8) = o1;
  }
}

// ---------------- causal flash attention ----------------
// grid (qt, bh); 4 waves/block, wave w owns q-rows [qt*64+16w, +16).
__global__ __launch_bounds__(256) void attn_kernel(const unsigned short* __restrict__ Qp,
                                                   const unsigned short* __restrict__ Kp,
                                                   const unsigned short* __restrict__ Vt,
                                                   unsigned short* __restrict__ Ob) {
  __shared__ unsigned short Klds[64 * 64];
  __shared__ unsigned short Vlds[64 * 64];
  __shared__ unsigned short Pbuf[4][16 * 72];
  const int qt = gridDim.x - 1 - blockIdx.x;   // long blocks launch first
  const int bh = blockIdx.y;
  const int tid = threadIdx.x, w = tid >> 6, l = tid & 63;
  const int lg = l >> 4, lr = l & 15;
  const int lr8 = l >> 3, lc8 = (l & 7) ^ lr8;
  const size_t hoff = (size_t)bh * T_ * D_;
  const int qrow = qt * 64 + w * 16 + lr;
  bf16x8 qf[2];
  qf[0] = *(const bf16x8*)(Qp + hoff + (size_t)qrow * D_ + lg * 8);
  qf[1] = *(const bf16x8*)(Qp + hoff + (size_t)qrow * D_ + 32 + lg * 8);
  f32x4 o[4];
#pragma unroll
  for (int dt = 0; dt < 4; ++dt) o[dt] = f32x4{0.f, 0.f, 0.f, 0.f};
  float mrow[4] = {-1e30f, -1e30f, -1e30f, -1e30f};
  float lsum[4] = {0.f, 0.f, 0.f, 0.f};

  for (int kt = 0; kt <= qt; ++kt) {
    __syncthreads();   // prior-iter LDS reads done
#pragma unroll
    for (int i = 0; i < 2; ++i) {
      const int ch = w + i * 4;   // 8 chunks of 1024B per tile
      gload_lds16(Kp + hoff + (size_t)(kt * 64 + ch * 8 + lr8) * D_ + lc8 * 8, &Klds[ch * 512]);
      gload_lds16(Vt + (size_t)bh * D_ * T_ + (size_t)(ch * 8 + lr8) * T_ + kt * 64 + lc8 * 8,
                  &Vlds[ch * 512]);
    }
    __syncthreads();   // vmcnt drained by compiler before barrier

    // S = Q K^T  (scale already folded into Q)
    f32x4 s[4];
#pragma unroll
    for (int nt = 0; nt < 4; ++nt) {
      s[nt] = f32x4{0.f, 0.f, 0.f, 0.f};
#pragma unroll
      for (int kc = 0; kc < 2; ++kc) {
        const int krow = nt * 16 + lr;
        const int c16 = (kc * 4 + lg) ^ (krow & 7);
        const bf16x8 kf = *(const bf16x8*)(&Klds[krow * 64 + c16 * 8]);
        s[nt] = __builtin_amdgcn_mfma_f32_16x16x32_bf16(qf[kc], kf, s[nt], 0, 0, 0);
      }
    }
    if (kt == qt) {   // diagonal tile: mask k_local > q_local
#pragma unroll
      for (int nt = 0; nt < 4; ++nt)
#pragma unroll
        for (int j = 0; j < 4; ++j)
          if (nt * 16 + lr > w * 16 + lg * 4 + j) s[nt][j] = -1e30f;
    }
    // online softmax: rows live in 16-lane groups -> butterfly reduce
#pragma unroll
    for (int j = 0; j < 4; ++j) {
      float mx = fmaxf(fmaxf(s[0][j], s[1][j]), fmaxf(s[2][j], s[3][j]));
      mx = fmaxf(mx, __shfl_xor(mx, 1));
      mx = fmaxf(mx, __shfl_xor(mx, 2));
      mx = fmaxf(mx, __shfl_xor(mx, 4));
      mx = fmaxf(mx, __shfl_xor(mx, 8));
      const float mn = fmaxf(mrow[j], mx);
      const float alpha = __expf(mrow[j] - mn);
      mrow[j] = mn;
      float rs = 0.f;
#pragma unroll
      for (int nt = 0; nt < 4; ++nt) {
        const float p = __expf(s[nt][j] - mn);
        s[nt][j] = p;
        rs += p;
      }
      rs += __shfl_xor(rs, 1);
      rs += __shfl_xor(rs, 2);
      rs += __shfl_xor(rs, 4);
      rs += __shfl_xor(rs, 8);
      lsum[j] = lsum[j] * alpha + rs;
#pragma unroll
      for (int dt = 0; dt < 4; ++dt) o[dt][j] *= alpha;
    }
    // P: C/D layout -> A-frag layout via per-wave LDS (wave-internal, no barrier)
    unsigned short* pb = &Pbuf[w][0];
#pragma unroll
    for (int nt = 0; nt < 4; ++nt)
#pragma unroll
      for (int j = 0; j < 4; ++j)
        pb[(lg * 4 + j) * 72 + nt * 16 + lr] = f2bf(s[nt][j]);
    bf16x8 pa[2];
#pragma unroll
    for (int kc = 0; kc < 2; ++kc)
      pa[kc] = *(const bf16x8*)(&pb[lr * 72 + kc * 32 + lg * 8]);
    // O += P V
#pragma unroll
    for (int dt = 0; dt < 4; ++dt)
#pragma unroll
      for (int kc = 0; kc < 2; ++kc) {
        const int vrow = dt * 16 + lr;
        const int c16 = (kc * 4 + lg) ^ (vrow & 7);
        const bf16x8 vf = *(const bf16x8*)(&Vlds[vrow * 64 + c16 * 8]);
        o[dt] = __builtin_amdgcn_mfma_f32_16x16x32_bf16(pa[kc], vf, o[dt], 0, 0, 0);
      }
  }
  // epilogue: O /= l, write to Ob[b*T+t][h*64+d] (bf16)
  const int b = bh >> 4, h = bh & 15;
#pragma unroll
  for (int dt = 0; dt < 4; ++dt)
#pragma unroll
    for (int j = 0; j < 4; ++j) {
      const int row = qt * 64 + w * 16 + lg * 4 + j;
      const int col = h * D_ + dt * 16 + lr;
      Ob[(size_t)(b * T_ + row) * C_ + col] = f2bf(o[dt][j] / lsum[j]);
    }
}

// ---------------- launch ----------------
extern "C" void kernel_launch(void* const* d_in, const int* in_sizes, int n_in,
                              void* d_out, int out_size, void* d_ws, size_t ws_size,
                              hipStream_t stream) {
  const float* x = (const float*)d_in[0];
  const float* Wqkv = (const float*)d_in[1];
  const float* Wout = (const float*)d_in[2];
  float* out = (float*)d_out;
  char* ws = (char*)d_ws;
  // workspace layout (72 MiB total)
  unsigned short* Xb    = (unsigned short*)(ws);                  //  8 MiB [4096][1024]
  unsigned short* WqkvT = (unsigned short*)(ws + (8ull << 20));   //  6 MiB [3072][1024]
  unsigned short* WoutT = (unsigned short*)(ws + (14ull << 20));  //  2 MiB [1024][1024]
  unsigned short* QKVb  = (unsigned short*)(ws + (16ull << 20));  // 24 MiB [4096][3072]
  unsigned short* Qp    = (unsigned short*)(ws + (40ull << 20));  //  8 MiB [32][2048][64]
  unsigned short* Kp    = (unsigned short*)(ws + (48ull << 20));  //  8 MiB
  unsigned short* Vt    = (unsigned short*)(ws + (56ull << 20));  //  8 MiB [32][64][2048]
  unsigned short* Ob    = (unsigned short*)(ws + (64ull << 20));  //  8 MiB [4096][1024]

  cvt_x_kernel<<<4096, 256, 0, stream>>>(x, Xb);
  tconv_kernel<<<dim3(N3_ / 32, C_ / 32), 256, 0, stream>>>(Wqkv, WqkvT, C_, N3_);
  tconv_kernel<<<dim3(C_ / 32, C_ / 32), 256, 0, stream>>>(Wout, WoutT, C_, C_);
  gemm_bt_kernel<0><<<dim3(N3_ / 128, (B_ * T_) / 128), 256, 0, stream>>>(
      Xb, WqkvT, QKVb, B_ * T_, N3_, C_);
  rope_pack_kernel<<<dim3(T_ / 64, B_ * H_), 256, 0, stream>>>(QKVb, Qp, Kp);
  vtrans_kernel<<<dim3(T_ / 64, B_ * H_), 256, 0, stream>>>(QKVb, Vt);
  attn_kernel<<<dim3(T_ / 64, B_ * H_), 256, 0, stream>>>(Qp, Kp, Vt, Ob);
  gemm_bt_kernel<1><<<dim3(C_ / 128, (B_ * T_) / 128), 256, 0, stream>>>(
      Ob, WoutT, out, B_ * T_, C_, C_);
}

// Round 2
// 172.123 us; speedup vs baseline: 1.1077x; 1.1077x over previous
//
#include <hip/hip_runtime.h>

// Problem: CausalSelfAttention  B=2 T=2048 C=1024 H=16 D=64, fp32 in/out.
// Pipeline: cvt(x) -> tconv(Wqkv,Wout) -> GEMM1(bf16) -> rope_pack -> vtrans
//           -> attn2 (swapped-QK 32x32 MFMA, in-register softmax, no LDS)
//           -> GEMM2(fp32 out).

#define B_  2
#define T_  2048
#define C_  1024
#define H_  16
#define D_  64
#define N3_ 3072

typedef unsigned short ushortx8 __attribute__((ext_vector_type(8)));
typedef unsigned short ushortx4 __attribute__((ext_vector_type(4)));
typedef short bf16x8 __attribute__((ext_vector_type(8)));
typedef float f32x4 __attribute__((ext_vector_type(4)));
typedef float f32x16 __attribute__((ext_vector_type(16)));
typedef unsigned int uintx2 __attribute__((ext_vector_type(2)));

__device__ __forceinline__ unsigned short f2bf(float f) {
  union { float f; unsigned u; } v; v.f = f;
  unsigned r = v.u + 0x7FFFu + ((v.u >> 16) & 1u);   // RNE
  return (unsigned short)(r >> 16);
}
__device__ __forceinline__ float bf2f(unsigned short h) {
  union { unsigned u; float f; } v; v.u = ((unsigned)h) << 16;
  return v.f;
}
// pack two f32 -> 2xbf16 in one u32 (no builtin exists; m240)
__device__ __forceinline__ unsigned cvtpk_bf16(float lo, float hi) {
  unsigned r; asm("v_cvt_pk_bf16_f32 %0, %1, %2" : "=v"(r) : "v"(lo), "v"(hi));
  return r;
}
// async global->LDS, 16B per lane; dst must be wave-uniform (HW adds lane*16)
__device__ __forceinline__ void gload_lds16(const void* g, void* l) {
  __builtin_amdgcn_global_load_lds((const __attribute__((address_space(1))) void*)g,
                                   (__attribute__((address_space(3))) void*)l,
                                   16, 0, 0);
}

// ---------------- fp32 -> bf16 convert (x) ----------------
__global__ __launch_bounds__(256) void cvt_x_kernel(const float* __restrict__ x,
                                                    unsigned short* __restrict__ xb) {
  size_t i = ((size_t)blockIdx.x * 256 + threadIdx.x) * 4;
  const float4 v = *(const float4*)(x + i);
  ushortx4 o;
  o[0] = f2bf(v.x); o[1] = f2bf(v.y); o[2] = f2bf(v.z); o[3] = f2bf(v.w);
  *(ushortx4*)(xb + i) = o;
}

// ------------- transpose+convert: W[K][N] f32 -> WT[N][K] bf16 -------------
__global__ __launch_bounds__(256) void tconv_kernel(const float* __restrict__ W,
                                                    unsigned short* __restrict__ WT,
                                                    int K, int N) {
  __shared__ float tile[32][33];
  const int n0 = blockIdx.x * 32, k0 = blockIdx.y * 32;
  const int tx = threadIdx.x & 31, ty = threadIdx.x >> 5;
#pragma unroll
  for (int i = 0; i < 4; ++i)
    tile[ty + i * 8][tx] = W[(size_t)(k0 + ty + i * 8) * N + n0 + tx];
  __syncthreads();
#pragma unroll
  for (int i = 0; i < 4; ++i)
    WT[(size_t)(n0 + ty + i * 8) * K + k0 + tx] = f2bf(tile[tx][ty + i * 8]);
}

// ---------------- GEMM: C[M][N] = A[M][K] * BT[N][K]^T (bf16 MFMA) ----------------
// 128x128 tile, BK=64, 4 waves (each 64x64), global_load_lds w/ XOR-swizzled source.
template <int OUTF32>
__global__ __launch_bounds__(256) void gemm_bt_kernel(const unsigned short* __restrict__ A,
                                                      const unsigned short* __restrict__ BT,
                                                      void* __restrict__ Cptr,
                                                      int M, int N, int K) {
  __shared__ unsigned short Alds[128 * 64];
  __shared__ unsigned short Blds[128 * 64];
  const int tid = threadIdx.x;
  const int w = tid >> 6, l = tid & 63;
  const int wr = w >> 1, wc = w & 1;
  const int lg = l >> 4, lr = l & 15;
  const int m0 = blockIdx.y * 128, n0 = blockIdx.x * 128;
  const int lr8 = l >> 3;                 // row within 8-row chunk
  const int lc8 = (l & 7) ^ lr8;          // pre-swizzled source col16 (T2 st-style)

  f32x4 acc[4][4];
#pragma unroll
  for (int i = 0; i < 4; ++i)
#pragma unroll
    for (int j = 0; j < 4; ++j) acc[i][j] = f32x4{0.f, 0.f, 0.f, 0.f};

  for (int k0 = 0; k0 < K; k0 += 64) {
    __syncthreads();
#pragma unroll
    for (int i = 0; i < 4; ++i) {
      const int ch = w * 4 + i;           // 16 chunks of 1024B per tile
      gload_lds16(A + (size_t)(m0 + ch * 8 + lr8) * K + k0 + lc8 * 8, &Alds[ch * 512]);
      gload_lds16(BT + (size_t)(n0 + ch * 8 + lr8) * K + k0 + lc8 * 8, &Blds[ch * 512]);
    }
    __syncthreads();
#pragma unroll
    for (int kc = 0; kc < 2; ++kc) {
      bf16x8 af[4], bfr[4];
#pragma unroll
      for (int mi = 0; mi < 4; ++mi) {
        const int row = wr * 64 + mi * 16 + lr;
        const int c16 = (kc * 4 + lg) ^ (row & 7);
        af[mi] = *(const bf16x8*)(&Alds[row * 64 + c16 * 8]);
      }
#pragma unroll
      for (int nj = 0; nj < 4; ++nj) {
        const int row = wc * 64 + nj * 16 + lr;
        const int c16 = (kc * 4 + lg) ^ (row & 7);
        bfr[nj] = *(const bf16x8*)(&Blds[row * 64 + c16 * 8]);
      }
#pragma unroll
      for (int mi = 0; mi < 4; ++mi)
#pragma unroll
        for (int nj = 0; nj < 4; ++nj)
          acc[mi][nj] = __builtin_amdgcn_mfma_f32_16x16x32_bf16(af[mi], bfr[nj], acc[mi][nj], 0, 0, 0);
    }
  }
#pragma unroll
  for (int mi = 0; mi < 4; ++mi)
#pragma unroll
    for (int nj = 0; nj < 4; ++nj)
#pragma unroll
      for (int j = 0; j < 4; ++j) {
        const int row = m0 + wr * 64 + mi * 16 + lg * 4 + j;  // C/D: row=(lane>>4)*4+j
        const int col = n0 + wc * 64 + nj * 16 + lr;          //      col=lane&15
        if (OUTF32) ((float*)Cptr)[(size_t)row * N + col] = acc[mi][nj][j];
        else ((unsigned short*)Cptr)[(size_t)row * N + col] = f2bf(acc[mi][nj][j]);
      }
}

// ------- RoPE + pack Q,K to [bh][T][64]; Q pre-scaled by log2e/sqrt(D) -------
__global__ __launch_bounds__(256) void rope_pack_kernel(const unsigned short* __restrict__ QKV,
                                                        unsigned short* __restrict__ Qp,
                                                        unsigned short* __restrict__ Kp) {
  const int tt = blockIdx.x, bh = blockIdx.y;
  const int b = bh >> 4, h = bh & 15;
  const int tid = threadIdx.x;
  const int half = tid >> 7;           // 0=q, 1=k
  const int r = (tid >> 1) & 63;
  const int d0 = (tid & 1) * 16;
  const int t = tt * 64 + r;
  const unsigned short* src = QKV + (size_t)(b * T_ + t) * N3_ + half * C_ + h * D_;
  ushortx8 lo0 = *(const ushortx8*)(src + d0);
  ushortx8 lo1 = *(const ushortx8*)(src + d0 + 8);
  ushortx8 hi0 = *(const ushortx8*)(src + d0 + 32);
  ushortx8 hi1 = *(const ushortx8*)(src + d0 + 40);
  ushortx8 olo0, olo1, ohi0, ohi1;
  // 1/sqrt(64) * log2(e) folded into q so attn softmax can use exp2 directly
  const float scale = half ? 1.0f : 0.18033688011112042f;
  const float tf = (float)t;
#pragma unroll
  for (int jj = 0; jj < 16; ++jj) {
    const int d = d0 + jj;
    // inv_freq = 10000^(-d/32) = 2^(-d*log2(10000)/32)
    const float invf = exp2f((float)d * -0.41524101186092036f);
    const float ang = tf * invf;
    const float c = cosf(ang), s = sinf(ang);
    const float xl = bf2f(jj < 8 ? lo0[jj] : lo1[jj - 8]);
    const float xh = bf2f(jj < 8 ? hi0[jj] : hi1[jj - 8]);
    const unsigned short rl = f2bf((xl * c - xh * s) * scale);
    const unsigned short rh = f2bf((xh * c + xl * s) * scale);
    if (jj < 8) { olo0[jj] = rl; ohi0[jj] = rh; }
    else        { olo1[jj - 8] = rl; ohi1[jj - 8] = rh; }
  }
  unsigned short* dst = (half ? Kp : Qp) + ((size_t)bh * T_ + t) * D_;
  *(ushortx8*)(dst + d0) = olo0;
  *(ushortx8*)(dst + d0 + 8) = olo1;
  *(ushortx8*)(dst + d0 + 32) = ohi0;
  *(ushortx8*)(dst + d0 + 40) = ohi1;
}

// ---------------- V transpose: qkv v-cols -> Vt[bh][64][T] ----------------
__global__ __launch_bounds__(256) void vtrans_kernel(const unsigned short* __restrict__ QKV,
                                                     unsigned short* __restrict__ Vt) {
  __shared__ unsigned short tile[64][72];
  const int tt = blockIdx.x, bh = blockIdx.y;
  const int b = bh >> 4, h = bh & 15;
  const int tid = threadIdx.x;
  {
    const int r = tid >> 2, seg = tid & 3;
    const unsigned short* src = QKV + (size_t)(b * T_ + tt * 64 + r) * N3_ + 2 * C_ + h * D_ + seg * 16;
    *(ushortx8*)(&tile[r][seg * 16]) = *(const ushortx8*)(src);
    *(ushortx8*)(&tile[r][seg * 16 + 8]) = *(const ushortx8*)(src + 8);
  }
  __syncthreads();
  {
    const int d = tid >> 2, ts = tid & 3;
    ushortx8 o0, o1;
#pragma unroll
    for (int i = 0; i < 8; ++i) { o0[i] = tile[ts * 16 + i][d]; o1[i] = tile[ts * 16 + 8 + i][d]; }
    unsigned short* dst = Vt + ((size_t)bh * D_ + d) * T_ + tt * 64 + ts * 16;
    *(ushortx8*)(dst) = o0;
    *(ushortx8*)(dst + 8) = o1;
  }
}

// ---------------- causal flash attention v2 ----------------
// Swapped-operand 32x32x16 MFMA, no LDS, no barriers. One wave = 32 q-rows.
// S^T = K.Q^T  (lane owns q = lane&31; 16 kv-values per lane, half in lane^32)
// O^T = V^T.P^T (lane owns same q; 32 d-values over regs) -> m/l lane-local.
// K/V read straight from L1/L2 (512KB/head; heads XCD-pinned via bid&7).
__global__ __launch_bounds__(256, 2) void attn2_kernel(const unsigned short* __restrict__ Qp,
                                                       const unsigned short* __restrict__ Kp,
                                                       const unsigned short* __restrict__ Vt,
                                                       unsigned short* __restrict__ Ob) {
  const int tid = threadIdx.x, w = tid >> 6, l = tid & 63;
  const int lq = l & 31, hi = l >> 5;
  const int bid = blockIdx.x;
  const int bh = (bid & 7) + 8 * ((bid >> 3) & 3);   // head-pin: bh's blocks share XCD (bid%8)
  const int sg = bid >> 5;                            // 0..15
  const int strip = 63 - (sg * 4 + w);                // long strips dispatch first
  const int q0 = strip * 32;
  const size_t koff = (size_t)bh * T_ * D_;

  // Q B-frags: lane holds Q[q0+lq][ds*16 + hi*8 + j]
  const unsigned short* qp = Qp + koff + (size_t)(q0 + lq) * D_ + hi * 8;
  bf16x8 qf[4];
#pragma unroll
  for (int ds = 0; ds < 4; ++ds) qf[ds] = *(const bf16x8*)(qp + ds * 16);

  f32x16 o0, o1;
#pragma unroll
  for (int r = 0; r < 16; ++r) { o0[r] = 0.f; o1[r] = 0.f; }
  float m = -3.0e38f, lden = 0.f;

  const unsigned short* kbase = Kp + koff + (size_t)lq * D_ + hi * 8;
  const unsigned short* vbase = Vt + (size_t)bh * D_ * T_ + (size_t)lq * T_ + hi * 8;

  bf16x8 kc[4];                       // K A-frags, double-buffered one chunk ahead
#pragma unroll
  for (int ds = 0; ds < 4; ++ds) kc[ds] = *(const bf16x8*)(kbase + ds * 16);

  for (int kt = 0; kt <= strip; ++kt) {
    const int kv0 = kt * 32;
    // V A-frags for this chunk: Vt[dt*32+lq][kv0 + ks*16 + hi*8]
    const bf16x8 vf0 = *(const bf16x8*)(vbase + kv0);
    const bf16x8 vf1 = *(const bf16x8*)(vbase + kv0 + 16);
    const bf16x8 vf2 = *(const bf16x8*)(vbase + 32 * T_ + kv0);
    const bf16x8 vf3 = *(const bf16x8*)(vbase + 32 * T_ + kv0 + 16);
    // K prefetch for next chunk (address-clamped, no divergence)
    const int ktn = (kt < strip) ? (kt + 1) : strip;
    bf16x8 kn[4];
#pragma unroll
    for (int ds = 0; ds < 4; ++ds)
      kn[ds] = *(const bf16x8*)(kbase + (size_t)ktn * 32 * D_ + ds * 16);

    // S^T = K . Q^T  over d=64
    f32x16 acc;
#pragma unroll
    for (int r = 0; r < 16; ++r) acc[r] = 0.f;
#pragma unroll
    for (int ds = 0; ds < 4; ++ds)
      acc = __builtin_amdgcn_mfma_f32_32x32x16_bf16(kc[ds], qf[ds], acc, 0, 0, 0);

    if (kt == strip) {   // diagonal: mask kv_local > q_local
#pragma unroll
      for (int r = 0; r < 16; ++r) {
        const int kvloc = (r & 3) + 8 * (r >> 2) + 4 * hi;
        if (kvloc > lq) acc[r] = -3.0e38f;
      }
    }
    // in-lane max tree (16) + cross-half permlane swap
    float mx[8];
#pragma unroll
    for (int i = 0; i < 8; ++i) mx[i] = fmaxf(acc[i], acc[i + 8]);
#pragma unroll
    for (int i = 0; i < 4; ++i) mx[i] = fmaxf(mx[i], mx[i + 4]);
    const float mloc = fmaxf(fmaxf(mx[0], mx[1]), fmaxf(mx[2], mx[3]));
    const uintx2 mp = __builtin_amdgcn_permlane32_swap(__float_as_uint(mloc), __float_as_uint(mloc), false, false);
    const float pm = fmaxf(__uint_as_float(mp.x), __uint_as_float(mp.y));
    const float mn = fmaxf(m, pm);
    const float alpha = __builtin_amdgcn_exp2f(m - mn);
    m = mn;
    float p[16];
#pragma unroll
    for (int r = 0; r < 16; ++r) p[r] = __builtin_amdgcn_exp2f(acc[r] - mn);
    float sm[8];
#pragma unroll
    for (int i = 0; i < 8; ++i) sm[i] = p[i] + p[i + 8];
#pragma unroll
    for (int i = 0; i < 4; ++i) sm[i] = sm[i] + sm[i + 4];
    const float sloc = (sm[0] + sm[1]) + (sm[2] + sm[3]);
    const uintx2 sp = __builtin_amdgcn_permlane32_swap(__float_as_uint(sloc), __float_as_uint(sloc), false, false);
    const float rs = __uint_as_float(sp.x) + __uint_as_float(sp.y);
    lden = lden * alpha + rs;
#pragma unroll
    for (int r = 0; r < 16; ++r) { o0[r] *= alpha; o1[r] *= alpha; }

    // P -> B-frags (T12): cvt_pk pairs, then swap x-hi <-> y-lo
    unsigned W0 = cvtpk_bf16(p[0], p[1]), W1 = cvtpk_bf16(p[2], p[3]);
    unsigned W2 = cvtpk_bf16(p[4], p[5]), W3 = cvtpk_bf16(p[6], p[7]);
    uintx2 Aa = __builtin_amdgcn_permlane32_swap(W0, W2, false, false);
    uintx2 Ab = __builtin_amdgcn_permlane32_swap(W1, W3, false, false);
    union { unsigned u[4]; bf16x8 v; } pf0 = {{Aa.x, Ab.x, Aa.y, Ab.y}};
    W0 = cvtpk_bf16(p[8], p[9]);  W1 = cvtpk_bf16(p[10], p[11]);
    W2 = cvtpk_bf16(p[12], p[13]); W3 = cvtpk_bf16(p[14], p[15]);
    Aa = __builtin_amdgcn_permlane32_swap(W0, W2, false, false);
    Ab = __builtin_amdgcn_permlane32_swap(W1, W3, false, false);
    union { unsigned u[4]; bf16x8 v; } pf1 = {{Aa.x, Ab.x, Aa.y, Ab.y}};

    // O^T += V^T . P^T
    o0 = __builtin_amdgcn_mfma_f32_32x32x16_bf16(vf0, pf0.v, o0, 0, 0, 0);
    o0 = __builtin_amdgcn_mfma_f32_32x32x16_bf16(vf1, pf1.v, o0, 0, 0, 0);
    o1 = __builtin_amdgcn_mfma_f32_32x32x16_bf16(vf2, pf0.v, o1, 0, 0, 0);
    o1 = __builtin_amdgcn_mfma_f32_32x32x16_bf16(vf3, pf1.v, o1, 0, 0, 0);

#pragma unroll
    for (int ds = 0; ds < 4; ++ds) kc[ds] = kn[ds];
  }
  // epilogue: O^T lane holds q=q0+lq, d = dt*32 + rq*8 + 4*hi + i
  const float rl = __builtin_amdgcn_rcpf(lden);
  const int b = bh >> 4, hh = bh & 15;
  unsigned short* orow = Ob + (size_t)(b * T_ + q0 + lq) * C_ + hh * D_ + 4 * hi;
#pragma unroll
  for (int rq = 0; rq < 4; ++rq) {
    ushortx4 ov0, ov1;
#pragma unroll
    for (int i = 0; i < 4; ++i) {
      ov0[i] = f2bf(o0[rq * 4 + i] * rl);
      ov1[i] = f2bf(o1[rq * 4 + i] * rl);
    }
    *(ushortx4*)(orow + rq * 8) = ov0;
    *(ushortx4*)(orow + 32 + rq * 8) = ov1;
  }
}

// ---------------- launch ----------------
extern "C" void kernel_launch(void* const* d_in, const int* in_sizes, int n_in,
                              void* d_out, int out_size, void* d_ws, size_t ws_size,
                              hipStream_t stream) {
  const float* x = (const float*)d_in[0];
  const float* Wqkv = (const float*)d_in[1];
  const float* Wout = (const float*)d_in[2];
  float* out = (float*)d_out;
  char* ws = (char*)d_ws;
  // workspace layout (72 MiB total)
  unsigned short* Xb    = (unsigned short*)(ws);                  //  8 MiB [4096][1024]
  unsigned short* WqkvT = (unsigned short*)(ws + (8ull << 20));   //  6 MiB [3072][1024]
  unsigned short* WoutT = (unsigned short*)(ws + (14ull << 20));  //  2 MiB [1024][1024]
  unsigned short* QKVb  = (unsigned short*)(ws + (16ull << 20));  // 24 MiB [4096][3072]
  unsigned short* Qp    = (unsigned short*)(ws + (40ull << 20));  //  8 MiB [32][2048][64]
  unsigned short* Kp    = (unsigned short*)(ws + (48ull << 20));  //  8 MiB
  unsigned short* Vt    = (unsigned short*)(ws + (56ull << 20));  //  8 MiB [32][64][2048]
  unsigned short* Ob    = (unsigned short*)(ws + (64ull << 20));  //  8 MiB [4096][1024]

  cvt_x_kernel<<<4096, 256, 0, stream>>>(x, Xb);
  tconv_kernel<<<dim3(N3_ / 32, C_ / 32), 256, 0, stream>>>(Wqkv, WqkvT, C_, N3_);
  tconv_kernel<<<dim3(C_ / 32, C_ / 32), 256, 0, stream>>>(Wout, WoutT, C_, C_);
  gemm_bt_kernel<0><<<dim3(N3_ / 128, (B_ * T_) / 128), 256, 0, stream>>>(
      Xb, WqkvT, QKVb, B_ * T_, N3_, C_);
  rope_pack_kernel<<<dim3(T_ / 64, B_ * H_), 256, 0, stream>>>(QKVb, Qp, Kp);
  vtrans_kernel<<<dim3(T_ / 64, B_ * H_), 256, 0, stream>>>(QKVb, Vt);
  attn2_kernel<<<512, 256, 0, stream>>>(Qp, Kp, Vt, Ob);
  gemm_bt_kernel<1><<<dim3(C_ / 128, (B_ * T_) / 128), 256, 0, stream>>>(
      Ob, WoutT, out, B_ * T_, C_, C_);
}

// Round 3
// 154.894 us; speedup vs baseline: 1.2309x; 1.1112x over previous
//
#include <hip/hip_runtime.h>

// Problem: CausalSelfAttention  B=2 T=2048 C=1024 H=16 D=64, fp32 in/out.
// Pipeline: cvt(x) -> tconv(Wqkv,Wout) -> GEMM1(bf16) -> rope_pack -> vtrans
//           -> attn3 (swapped-QK 32x32 MFMA, kv-split x4, in-block merge)
//           -> GEMM2(fp32 out).

#define B_  2
#define T_  2048
#define C_  1024
#define H_  16
#define D_  64
#define N3_ 3072

typedef unsigned short ushortx8 __attribute__((ext_vector_type(8)));
typedef unsigned short ushortx4 __attribute__((ext_vector_type(4)));
typedef short bf16x8 __attribute__((ext_vector_type(8)));
typedef float f32x4 __attribute__((ext_vector_type(4)));
typedef float f32x16 __attribute__((ext_vector_type(16)));
typedef unsigned int uintx2 __attribute__((ext_vector_type(2)));

__device__ __forceinline__ unsigned short f2bf(float f) {
  union { float f; unsigned u; } v; v.f = f;
  unsigned r = v.u + 0x7FFFu + ((v.u >> 16) & 1u);   // RNE
  return (unsigned short)(r >> 16);
}
__device__ __forceinline__ float bf2f(unsigned short h) {
  union { unsigned u; float f; } v; v.u = ((unsigned)h) << 16;
  return v.f;
}
// pack two f32 -> 2xbf16 in one u32 (no builtin exists; m240)
__device__ __forceinline__ unsigned cvtpk_bf16(float lo, float hi) {
  unsigned r; asm("v_cvt_pk_bf16_f32 %0, %1, %2" : "=v"(r) : "v"(lo), "v"(hi));
  return r;
}
// async global->LDS, 16B per lane; dst must be wave-uniform (HW adds lane*16)
__device__ __forceinline__ void gload_lds16(const void* g, void* l) {
  __builtin_amdgcn_global_load_lds((const __attribute__((address_space(1))) void*)g,
                                   (__attribute__((address_space(3))) void*)l,
                                   16, 0, 0);
}

// ---------------- fp32 -> bf16 convert (x) ----------------
__global__ __launch_bounds__(256) void cvt_x_kernel(const float* __restrict__ x,
                                                    unsigned short* __restrict__ xb) {
  size_t i = ((size_t)blockIdx.x * 256 + threadIdx.x) * 4;
  const float4 v = *(const float4*)(x + i);
  ushortx4 o;
  o[0] = f2bf(v.x); o[1] = f2bf(v.y); o[2] = f2bf(v.z); o[3] = f2bf(v.w);
  *(ushortx4*)(xb + i) = o;
}

// ------------- transpose+convert: W[K][N] f32 -> WT[N][K] bf16 -------------
__global__ __launch_bounds__(256) void tconv_kernel(const float* __restrict__ W,
                                                    unsigned short* __restrict__ WT,
                                                    int K, int N) {
  __shared__ float tile[32][33];
  const int n0 = blockIdx.x * 32, k0 = blockIdx.y * 32;
  const int tx = threadIdx.x & 31, ty = threadIdx.x >> 5;
#pragma unroll
  for (int i = 0; i < 4; ++i)
    tile[ty + i * 8][tx] = W[(size_t)(k0 + ty + i * 8) * N + n0 + tx];
  __syncthreads();
#pragma unroll
  for (int i = 0; i < 4; ++i)
    WT[(size_t)(n0 + ty + i * 8) * K + k0 + tx] = f2bf(tile[tx][ty + i * 8]);
}

// ---------------- GEMM: C[M][N] = A[M][K] * BT[N][K]^T (bf16 MFMA) ----------------
// 128x128 tile, BK=64, 4 waves (each 64x64), global_load_lds w/ XOR-swizzled source.
template <int OUTF32>
__global__ __launch_bounds__(256) void gemm_bt_kernel(const unsigned short* __restrict__ A,
                                                      const unsigned short* __restrict__ BT,
                                                      void* __restrict__ Cptr,
                                                      int M, int N, int K) {
  __shared__ unsigned short Alds[128 * 64];
  __shared__ unsigned short Blds[128 * 64];
  const int tid = threadIdx.x;
  const int w = tid >> 6, l = tid & 63;
  const int wr = w >> 1, wc = w & 1;
  const int lg = l >> 4, lr = l & 15;
  const int m0 = blockIdx.y * 128, n0 = blockIdx.x * 128;
  const int lr8 = l >> 3;                 // row within 8-row chunk
  const int lc8 = (l & 7) ^ lr8;          // pre-swizzled source col16 (T2 st-style)

  f32x4 acc[4][4];
#pragma unroll
  for (int i = 0; i < 4; ++i)
#pragma unroll
    for (int j = 0; j < 4; ++j) acc[i][j] = f32x4{0.f, 0.f, 0.f, 0.f};

  for (int k0 = 0; k0 < K; k0 += 64) {
    __syncthreads();
#pragma unroll
    for (int i = 0; i < 4; ++i) {
      const int ch = w * 4 + i;           // 16 chunks of 1024B per tile
      gload_lds16(A + (size_t)(m0 + ch * 8 + lr8) * K + k0 + lc8 * 8, &Alds[ch * 512]);
      gload_lds16(BT + (size_t)(n0 + ch * 8 + lr8) * K + k0 + lc8 * 8, &Blds[ch * 512]);
    }
    __syncthreads();
#pragma unroll
    for (int kc = 0; kc < 2; ++kc) {
      bf16x8 af[4], bfr[4];
#pragma unroll
      for (int mi = 0; mi < 4; ++mi) {
        const int row = wr * 64 + mi * 16 + lr;
        const int c16 = (kc * 4 + lg) ^ (row & 7);
        af[mi] = *(const bf16x8*)(&Alds[row * 64 + c16 * 8]);
      }
#pragma unroll
      for (int nj = 0; nj < 4; ++nj) {
        const int row = wc * 64 + nj * 16 + lr;
        const int c16 = (kc * 4 + lg) ^ (row & 7);
        bfr[nj] = *(const bf16x8*)(&Blds[row * 64 + c16 * 8]);
      }
#pragma unroll
      for (int mi = 0; mi < 4; ++mi)
#pragma unroll
        for (int nj = 0; nj < 4; ++nj)
          acc[mi][nj] = __builtin_amdgcn_mfma_f32_16x16x32_bf16(af[mi], bfr[nj], acc[mi][nj], 0, 0, 0);
    }
  }
#pragma unroll
  for (int mi = 0; mi < 4; ++mi)
#pragma unroll
    for (int nj = 0; nj < 4; ++nj)
#pragma unroll
      for (int j = 0; j < 4; ++j) {
        const int row = m0 + wr * 64 + mi * 16 + lg * 4 + j;  // C/D: row=(lane>>4)*4+j
        const int col = n0 + wc * 64 + nj * 16 + lr;          //      col=lane&15
        if (OUTF32) ((float*)Cptr)[(size_t)row * N + col] = acc[mi][nj][j];
        else ((unsigned short*)Cptr)[(size_t)row * N + col] = f2bf(acc[mi][nj][j]);
      }
}

// ------- RoPE + pack Q,K to [bh][T][64]; Q pre-scaled by log2e/sqrt(D) -------
__global__ __launch_bounds__(256) void rope_pack_kernel(const unsigned short* __restrict__ QKV,
                                                        unsigned short* __restrict__ Qp,
                                                        unsigned short* __restrict__ Kp) {
  const int tt = blockIdx.x, bh = blockIdx.y;
  const int b = bh >> 4, h = bh & 15;
  const int tid = threadIdx.x;
  const int half = tid >> 7;           // 0=q, 1=k
  const int r = (tid >> 1) & 63;
  const int d0 = (tid & 1) * 16;
  const int t = tt * 64 + r;
  const unsigned short* src = QKV + (size_t)(b * T_ + t) * N3_ + half * C_ + h * D_;
  ushortx8 lo0 = *(const ushortx8*)(src + d0);
  ushortx8 lo1 = *(const ushortx8*)(src + d0 + 8);
  ushortx8 hi0 = *(const ushortx8*)(src + d0 + 32);
  ushortx8 hi1 = *(const ushortx8*)(src + d0 + 40);
  ushortx8 olo0, olo1, ohi0, ohi1;
  // 1/sqrt(64) * log2(e) folded into q so attn softmax can use exp2 directly
  const float scale = half ? 1.0f : 0.18033688011112042f;
  const float tf = (float)t;
#pragma unroll
  for (int jj = 0; jj < 16; ++jj) {
    const int d = d0 + jj;
    // inv_freq = 10000^(-d/32) = 2^(-d*log2(10000)/32)
    const float invf = exp2f((float)d * -0.41524101186092036f);
    const float ang = tf * invf;
    const float c = cosf(ang), s = sinf(ang);
    const float xl = bf2f(jj < 8 ? lo0[jj] : lo1[jj - 8]);
    const float xh = bf2f(jj < 8 ? hi0[jj] : hi1[jj - 8]);
    const unsigned short rl = f2bf((xl * c - xh * s) * scale);
    const unsigned short rh = f2bf((xh * c + xl * s) * scale);
    if (jj < 8) { olo0[jj] = rl; ohi0[jj] = rh; }
    else        { olo1[jj - 8] = rl; ohi1[jj - 8] = rh; }
  }
  unsigned short* dst = (half ? Kp : Qp) + ((size_t)bh * T_ + t) * D_;
  *(ushortx8*)(dst + d0) = olo0;
  *(ushortx8*)(dst + d0 + 8) = olo1;
  *(ushortx8*)(dst + d0 + 32) = ohi0;
  *(ushortx8*)(dst + d0 + 40) = ohi1;
}

// ---------------- V transpose: qkv v-cols -> Vt[bh][64][T] ----------------
__global__ __launch_bounds__(256) void vtrans_kernel(const unsigned short* __restrict__ QKV,
                                                     unsigned short* __restrict__ Vt) {
  __shared__ unsigned short tile[64][72];
  const int tt = blockIdx.x, bh = blockIdx.y;
  const int b = bh >> 4, h = bh & 15;
  const int tid = threadIdx.x;
  {
    const int r = tid >> 2, seg = tid & 3;
    const unsigned short* src = QKV + (size_t)(b * T_ + tt * 64 + r) * N3_ + 2 * C_ + h * D_ + seg * 16;
    *(ushortx8*)(&tile[r][seg * 16]) = *(const ushortx8*)(src);
    *(ushortx8*)(&tile[r][seg * 16 + 8]) = *(const ushortx8*)(src + 8);
  }
  __syncthreads();
  {
    const int d = tid >> 2, ts = tid & 3;
    ushortx8 o0, o1;
#pragma unroll
    for (int i = 0; i < 8; ++i) { o0[i] = tile[ts * 16 + i][d]; o1[i] = tile[ts * 16 + 8 + i][d]; }
    unsigned short* dst = Vt + ((size_t)bh * D_ + d) * T_ + tt * 64 + ts * 16;
    *(ushortx8*)(dst) = o0;
    *(ushortx8*)(dst + 8) = o1;
  }
}

// ---------------- causal flash attention v3: kv-split x4 ----------------
// One block = one 32-row q-strip; wave w handles kv-chunks kt = w, w+4, ...
// Swapped-operand 32x32x16 MFMA, in-register softmax (no LDS in main loop).
// Partials (m, l, O^T) merged in-block via bf16 LDS at the end.
__global__ __launch_bounds__(256, 4) void attn3_kernel(const unsigned short* __restrict__ Qp,
                                                       const unsigned short* __restrict__ Kp,
                                                       const unsigned short* __restrict__ Vt,
                                                       unsigned short* __restrict__ Ob) {
  __shared__ unsigned short plds[4][64][40];  // [wave][lane][32 bf16 + pad] 20.5KB
  __shared__ float mlds[2][4][32];            // [m/l][wave][q]
  const int tid = threadIdx.x, w = tid >> 6, l = tid & 63;
  const int lq = l & 31, hi = l >> 5;
  const int bid = blockIdx.x;
  const int bh = (bid & 7) + 8 * ((bid >> 3) & 3);  // same-bh blocks -> same XCD (bid%8)
  const int strip = 63 - (bid >> 5);                // long strips dispatch first
  const int q0 = strip * 32;
  const size_t koff = (size_t)bh * T_ * D_;

  // Q B-frags: lane holds Q[q0+lq][ds*16 + hi*8 + j] (all 4 waves identical)
  const unsigned short* qp = Qp + koff + (size_t)(q0 + lq) * D_ + hi * 8;
  bf16x8 qf[4];
#pragma unroll
  for (int ds = 0; ds < 4; ++ds) qf[ds] = *(const bf16x8*)(qp + ds * 16);

  f32x16 o0, o1;
#pragma unroll
  for (int r = 0; r < 16; ++r) { o0[r] = 0.f; o1[r] = 0.f; }
  float m = -3.0e38f, lden = 0.f;

  const unsigned short* kbase = Kp + koff + (size_t)lq * D_ + hi * 8;
  const unsigned short* vbase = Vt + (size_t)bh * D_ * T_ + (size_t)lq * T_ + hi * 8;

  if (strip >= w) {
    bf16x8 kc[4];                     // K A-frags, register double-buffer
#pragma unroll
    for (int ds = 0; ds < 4; ++ds)
      kc[ds] = *(const bf16x8*)(kbase + (size_t)w * 32 * D_ + ds * 16);

    for (int kt = w; kt <= strip; kt += 4) {
      const int kv0 = kt * 32;
      // V A-frags: Vt[dt*32 + lq][kv0 + ks*16 + hi*8]
      const bf16x8 vf0 = *(const bf16x8*)(vbase + kv0);
      const bf16x8 vf1 = *(const bf16x8*)(vbase + kv0 + 16);
      const bf16x8 vf2 = *(const bf16x8*)(vbase + 32 * T_ + kv0);
      const bf16x8 vf3 = *(const bf16x8*)(vbase + 32 * T_ + kv0 + 16);
      // K prefetch for next chunk (clamped, no divergence)
      const int ktn = (kt + 4 <= strip) ? kt + 4 : kt;
      bf16x8 kn[4];
#pragma unroll
      for (int ds = 0; ds < 4; ++ds)
        kn[ds] = *(const bf16x8*)(kbase + (size_t)ktn * 32 * D_ + ds * 16);

      // S^T = K . Q^T  over d=64
      f32x16 acc;
#pragma unroll
      for (int r = 0; r < 16; ++r) acc[r] = 0.f;
#pragma unroll
      for (int ds = 0; ds < 4; ++ds)
        acc = __builtin_amdgcn_mfma_f32_32x32x16_bf16(kc[ds], qf[ds], acc, 0, 0, 0);

      if (kt == strip) {   // diagonal: mask kv_local > q_local
#pragma unroll
        for (int r = 0; r < 16; ++r) {
          const int kvloc = (r & 3) + 8 * (r >> 2) + 4 * hi;
          if (kvloc > lq) acc[r] = -3.0e38f;
        }
      }
      // in-lane max tree (15) + cross-half permlane swap
      float mx[8];
#pragma unroll
      for (int i = 0; i < 8; ++i) mx[i] = fmaxf(acc[i], acc[i + 8]);
#pragma unroll
      for (int i = 0; i < 4; ++i) mx[i] = fmaxf(mx[i], mx[i + 4]);
      const float mloc = fmaxf(fmaxf(mx[0], mx[1]), fmaxf(mx[2], mx[3]));
      const uintx2 mp = __builtin_amdgcn_permlane32_swap(__float_as_uint(mloc), __float_as_uint(mloc), false, false);
      const float pm = fmaxf(__uint_as_float(mp.x), __uint_as_float(mp.y));
      const float mn = fmaxf(m, pm);
      const float alpha = __builtin_amdgcn_exp2f(m - mn);
      m = mn;
      float p[16];
#pragma unroll
      for (int r = 0; r < 16; ++r) p[r] = __builtin_amdgcn_exp2f(acc[r] - mn);
      float sm[8];
#pragma unroll
      for (int i = 0; i < 8; ++i) sm[i] = p[i] + p[i + 8];
#pragma unroll
      for (int i = 0; i < 4; ++i) sm[i] = sm[i] + sm[i + 4];
      const float sloc = (sm[0] + sm[1]) + (sm[2] + sm[3]);
      const uintx2 sp = __builtin_amdgcn_permlane32_swap(__float_as_uint(sloc), __float_as_uint(sloc), false, false);
      const float rs = __uint_as_float(sp.x) + __uint_as_float(sp.y);
      lden = lden * alpha + rs;
#pragma unroll
      for (int r = 0; r < 16; ++r) { o0[r] *= alpha; o1[r] *= alpha; }

      // P -> B-frags (T12): cvt_pk pairs, then swap x-hi <-> y-lo
      unsigned W0 = cvtpk_bf16(p[0], p[1]), W1 = cvtpk_bf16(p[2], p[3]);
      unsigned W2 = cvtpk_bf16(p[4], p[5]), W3 = cvtpk_bf16(p[6], p[7]);
      uintx2 Aa = __builtin_amdgcn_permlane32_swap(W0, W2, false, false);
      uintx2 Ab = __builtin_amdgcn_permlane32_swap(W1, W3, false, false);
      union { unsigned u[4]; bf16x8 v; } pf0 = {{Aa.x, Ab.x, Aa.y, Ab.y}};
      W0 = cvtpk_bf16(p[8], p[9]);  W1 = cvtpk_bf16(p[10], p[11]);
      W2 = cvtpk_bf16(p[12], p[13]); W3 = cvtpk_bf16(p[14], p[15]);
      Aa = __builtin_amdgcn_permlane32_swap(W0, W2, false, false);
      Ab = __builtin_amdgcn_permlane32_swap(W1, W3, false, false);
      union { unsigned u[4]; bf16x8 v; } pf1 = {{Aa.x, Ab.x, Aa.y, Ab.y}};

      // O^T += V^T . P^T
      o0 = __builtin_amdgcn_mfma_f32_32x32x16_bf16(vf0, pf0.v, o0, 0, 0, 0);
      o0 = __builtin_amdgcn_mfma_f32_32x32x16_bf16(vf1, pf1.v, o0, 0, 0, 0);
      o1 = __builtin_amdgcn_mfma_f32_32x32x16_bf16(vf2, pf0.v, o1, 0, 0, 0);
      o1 = __builtin_amdgcn_mfma_f32_32x32x16_bf16(vf3, pf1.v, o1, 0, 0, 0);

#pragma unroll
      for (int ds = 0; ds < 4; ++ds) kc[ds] = kn[ds];
    }
  }

  // ---- write partials (unnormalized O^T as bf16; m, l as f32) ----
  {
    unsigned short* prow = &plds[w][l][0];
#pragma unroll
    for (int j = 0; j < 16; ++j) { prow[j] = f2bf(o0[j]); prow[16 + j] = f2bf(o1[j]); }
    if (hi == 0) { mlds[0][w][lq] = m; mlds[1][w][lq] = lden; }
  }
  __syncthreads();

  // ---- distributed merge: wave w merges reg-slice rq = w ----
  float mw[4], lw[4];
#pragma unroll
  for (int w2 = 0; w2 < 4; ++w2) { mw[w2] = mlds[0][w2][lq]; lw[w2] = mlds[1][w2][lq]; }
  const float M = fmaxf(fmaxf(mw[0], mw[1]), fmaxf(mw[2], mw[3]));
  float fw[4], L = 0.f;
#pragma unroll
  for (int w2 = 0; w2 < 4; ++w2) { fw[w2] = __builtin_amdgcn_exp2f(mw[w2] - M); L += lw[w2] * fw[w2]; }
  float a0[4] = {0.f, 0.f, 0.f, 0.f}, a1[4] = {0.f, 0.f, 0.f, 0.f};
#pragma unroll
  for (int w2 = 0; w2 < 4; ++w2) {
    const unsigned short* r2 = &plds[w2][l][0];
#pragma unroll
    for (int i = 0; i < 4; ++i) {
      a0[i] += fw[w2] * bf2f(r2[w * 4 + i]);
      a1[i] += fw[w2] * bf2f(r2[16 + w * 4 + i]);
    }
  }
  const float rl = __builtin_amdgcn_rcpf(L);
  // lane holds q = q0+lq; merged d = w*8 + 4*hi + i (o0) and +32 (o1)
  const int b = bh >> 4, hh = bh & 15;
  unsigned short* orow = Ob + (size_t)(b * T_ + q0 + lq) * C_ + hh * D_ + 4 * hi;
  ushortx4 ov0, ov1;
#pragma unroll
  for (int i = 0; i < 4; ++i) { ov0[i] = f2bf(a0[i] * rl); ov1[i] = f2bf(a1[i] * rl); }
  *(ushortx4*)(orow + w * 8) = ov0;
  *(ushortx4*)(orow + 32 + w * 8) = ov1;
}

// ---------------- launch ----------------
extern "C" void kernel_launch(void* const* d_in, const int* in_sizes, int n_in,
                              void* d_out, int out_size, void* d_ws, size_t ws_size,
                              hipStream_t stream) {
  const float* x = (const float*)d_in[0];
  const float* Wqkv = (const float*)d_in[1];
  const float* Wout = (const float*)d_in[2];
  float* out = (float*)d_out;
  char* ws = (char*)d_ws;
  // workspace layout (72 MiB total)
  unsigned short* Xb    = (unsigned short*)(ws);                  //  8 MiB [4096][1024]
  unsigned short* WqkvT = (unsigned short*)(ws + (8ull << 20));   //  6 MiB [3072][1024]
  unsigned short* WoutT = (unsigned short*)(ws + (14ull << 20));  //  2 MiB [1024][1024]
  unsigned short* QKVb  = (unsigned short*)(ws + (16ull << 20));  // 24 MiB [4096][3072]
  unsigned short* Qp    = (unsigned short*)(ws + (40ull << 20));  //  8 MiB [32][2048][64]
  unsigned short* Kp    = (unsigned short*)(ws + (48ull << 20));  //  8 MiB
  unsigned short* Vt    = (unsigned short*)(ws + (56ull << 20));  //  8 MiB [32][64][2048]
  unsigned short* Ob    = (unsigned short*)(ws + (64ull << 20));  //  8 MiB [4096][1024]

  cvt_x_kernel<<<4096, 256, 0, stream>>>(x, Xb);
  tconv_kernel<<<dim3(N3_ / 32, C_ / 32), 256, 0, stream>>>(Wqkv, WqkvT, C_, N3_);
  tconv_kernel<<<dim3(C_ / 32, C_ / 32), 256, 0, stream>>>(Wout, WoutT, C_, C_);
  gemm_bt_kernel<0><<<dim3(N3_ / 128, (B_ * T_) / 128), 256, 0, stream>>>(
      Xb, WqkvT, QKVb, B_ * T_, N3_, C_);
  rope_pack_kernel<<<dim3(T_ / 64, B_ * H_), 256, 0, stream>>>(QKVb, Qp, Kp);
  vtrans_kernel<<<dim3(T_ / 64, B_ * H_), 256, 0, stream>>>(QKVb, Vt);
  attn3_kernel<<<2048, 256, 0, stream>>>(Qp, Kp, Vt, Ob);
  gemm_bt_kernel<1><<<dim3(C_ / 128, (B_ * T_) / 128), 256, 0, stream>>>(
      Ob, WoutT, out, B_ * T_, C_, C_);
}